// Round 1
// baseline (1440.358 us; speedup 1.0000x reference)
//
#include <hip/hip_runtime.h>
#include <hip/hip_bf16.h>
#include <math.h>

#define B_ 4
#define S_ 2048
#define DM_ 2048

// Full-wave (64-lane) sum via DPP row_shr/row_bcast (gfx9/CDNA sequence),
// result broadcast to all lanes through readlane(63) -> SGPR.
__device__ __forceinline__ float wave_reduce_add_f32(float x) {
  float t;
  t = __int_as_float(__builtin_amdgcn_update_dpp(0, __float_as_int(x), 0x111, 0xf, 0xf, true)); x += t; // row_shr:1
  t = __int_as_float(__builtin_amdgcn_update_dpp(0, __float_as_int(x), 0x112, 0xf, 0xf, true)); x += t; // row_shr:2
  t = __int_as_float(__builtin_amdgcn_update_dpp(0, __float_as_int(x), 0x114, 0xf, 0xf, true)); x += t; // row_shr:4
  t = __int_as_float(__builtin_amdgcn_update_dpp(0, __float_as_int(x), 0x118, 0xf, 0xf, true)); x += t; // row_shr:8
  t = __int_as_float(__builtin_amdgcn_update_dpp(0, __float_as_int(x), 0x142, 0xa, 0xf, true)); x += t; // row_bcast:15
  t = __int_as_float(__builtin_amdgcn_update_dpp(0, __float_as_int(x), 0x143, 0xc, 0xf, true)); x += t; // row_bcast:31
  return __int_as_float(__builtin_amdgcn_readlane(__float_as_int(x), 63));
}

// ---------------------------------------------------------------------------
// K1: fused projections. proj[row][0:64]=k(l2norm) [64:128]=v [128:192]=q(l2norm)
// [192:256]=alpha. Block = 16 rows x 256 cols, 512 blocks, fp32 LDS-tiled GEMM.
// ---------------------------------------------------------------------------
__global__ __launch_bounds__(256) void k_proj(
    const float* __restrict__ x, const float* __restrict__ Wk,
    const float* __restrict__ Wv, const float* __restrict__ Wq,
    const float* __restrict__ Wa, const float* __restrict__ Wab,
    const float* __restrict__ lam, float* __restrict__ proj)
{
  __shared__ __align__(16) float xs[16 * 40];    // [row][k], stride 40 (b128-aligned, 2-way banks)
  __shared__ __align__(16) float ws[32 * 260];   // [k][col], stride 260 (4-float bank rotation)
  const int tid = threadIdx.x;
  const int r0  = blockIdx.x * 16;
  const int ct  = tid & 63;    // col-thread: cols ct + 64j (j = matrix index)
  const int rt  = tid >> 6;    // row-thread: rows rt*4 + r  (== wave id)
  float acc[4][4];
  #pragma unroll
  for (int r = 0; r < 4; r++) { acc[r][0] = 0.f; acc[r][1] = 0.f; acc[r][2] = 0.f; acc[r][3] = 0.f; }

  const int sg = tid >> 3;     // 0..31
  const int sm = tid & 7;      // 0..7
  const float* wbase[4] = {Wk, Wv, Wq, Wa};

  for (int k0 = 0; k0 < DM_; k0 += 32) {
    if (tid < 128) {
      const int rr = tid >> 3;
      const int ko = (tid & 7) << 2;
      float4 xv = *(const float4*)(x + (size_t)(r0 + rr) * DM_ + k0 + ko);
      *(float4*)(xs + rr * 40 + ko) = xv;
    }
    #pragma unroll
    for (int p = 0; p < 8; p++) {
      const int c = sg + p * 32;
      const float* wb = wbase[p >> 1];
      const int cc = c - (p >> 1) * 64;
      float4 wv = *(const float4*)(wb + (size_t)cc * DM_ + k0 + sm * 4);
      ws[(sm * 4 + 0) * 260 + c] = wv.x;
      ws[(sm * 4 + 1) * 260 + c] = wv.y;
      ws[(sm * 4 + 2) * 260 + c] = wv.z;
      ws[(sm * 4 + 3) * 260 + c] = wv.w;
    }
    __syncthreads();
    #pragma unroll
    for (int kq = 0; kq < 8; kq++) {
      float4 xv[4];
      #pragma unroll
      for (int r = 0; r < 4; r++) xv[r] = *(const float4*)(xs + (rt * 4 + r) * 40 + kq * 4);
      #pragma unroll
      for (int i = 0; i < 4; i++) {
        const int kk = kq * 4 + i;
        float wv0 = ws[kk * 260 + ct];
        float wv1 = ws[kk * 260 + ct + 64];
        float wv2 = ws[kk * 260 + ct + 128];
        float wv3 = ws[kk * 260 + ct + 192];
        #pragma unroll
        for (int r = 0; r < 4; r++) {
          float xr = (i == 0) ? xv[r].x : (i == 1) ? xv[r].y : (i == 2) ? xv[r].z : xv[r].w;
          acc[r][0] = fmaf(xr, wv0, acc[r][0]);
          acc[r][1] = fmaf(xr, wv1, acc[r][1]);
          acc[r][2] = fmaf(xr, wv2, acc[r][2]);
          acc[r][3] = fmaf(xr, wv3, acc[r][3]);
        }
      }
    }
    __syncthreads();
  }
  // epilogue: l2norm for k,q across the 64 lanes of this wave; sigmoid/alpha for a
  float lamv = lam[ct];
  float la = logf(1.f / (1.f + expf(-lamv)) + 1e-8f);
  float bv = Wab[ct];
  #pragma unroll
  for (int r = 0; r < 4; r++) {
    float nk = wave_reduce_add_f32(acc[r][0] * acc[r][0]);
    float nq = wave_reduce_add_f32(acc[r][2] * acc[r][2]);
    nk = fmaxf(sqrtf(nk), 1e-12f);
    nq = fmaxf(sqrtf(nq), 1e-12f);
    float pre = acc[r][3] + bv;
    float rr_ = 1.f / (1.f + expf(-pre));
    float al  = expf(8.f * rr_ * la);
    float* pr = proj + (size_t)(r0 + rt * 4 + r) * 256;
    pr[ct]        = acc[r][0] / nk;
    pr[64 + ct]   = acc[r][1];
    pr[128 + ct]  = acc[r][2] / nq;
    pr[192 + ct]  = al;
  }
}

// ---------------------------------------------------------------------------
// K2: the sequential scan. 1 block per batch, 4 waves; wave w owns H rows
// [16w,16w+16), lane owns column v. H entirely in VGPRs. Ping-pong LDS for
// the per-step input vector + cross-wave matvec partials; 2 barriers/step.
// y written as 4 per-wave partials (summed in K3) to avoid a 3rd barrier.
// ---------------------------------------------------------------------------
__global__ __launch_bounds__(256) void k_scan(const float* __restrict__ proj,
                                              float* __restrict__ ypart)
{
  __shared__ __align__(16) float inv[2][256];
  __shared__ __align__(16) float red[2][2][4][64];
  const int b    = blockIdx.x;
  const int tid  = threadIdx.x;
  const int w    = tid >> 6;
  const int lane = tid & 63;
  const int kb   = w * 16;
  float H[16];
  #pragma unroll
  for (int j = 0; j < 16; j++) H[j] = 0.f;
  const float* pb = proj + (size_t)b * S_ * 256;
  float* yb = ypart + (size_t)b * S_ * 256;
  float pf0 = pb[tid];
  float pf1 = pb[256 + tid];
  for (int t = 0; t < S_; t++) {
    const int pp = t & 1;
    inv[pp][tid] = pf0;
    pf0 = pf1;
    pf1 = (t + 2 < S_) ? pb[(size_t)(t + 2) * 256 + tid] : 0.f;  // 2-deep prefetch
    __syncthreads();
    float k_[16], q_[16], a_[16];
    #pragma unroll
    for (int jq = 0; jq < 4; jq++) {
      *(float4*)(k_ + jq * 4) = *(const float4*)(&inv[pp][kb + jq * 4]);
      *(float4*)(q_ + jq * 4) = *(const float4*)(&inv[pp][128 + kb + jq * 4]);
      *(float4*)(a_ + jq * 4) = *(const float4*)(&inv[pp][192 + kb + jq * 4]);
    }
    float vv = inv[pp][64 + lane];
    float pred_p = 0.f, kH_p = 0.f;
    #pragma unroll
    for (int j = 0; j < 16; j++) {
      pred_p = fmaf(q_[j], H[j], pred_p);
      kH_p   = fmaf(k_[j], H[j], kH_p);
    }
    red[pp][0][w][lane] = pred_p;
    red[pp][1][w][lane] = kH_p;
    __syncthreads();
    float pred = (red[pp][0][0][lane] + red[pp][0][1][lane]) + (red[pp][0][2][lane] + red[pp][0][3][lane]);
    float kH   = (red[pp][1][0][lane] + red[pp][1][1][lane]) + (red[pp][1][2][lane] + red[pp][1][3][lane]);
    float d = vv - pred;
    float e = wave_reduce_add_f32(d * d);
    float s = 1.f / (1.f + expf(-e * (1.f / 1.000001f)));
    float g = s * (vv - kH);
    float yp = 0.f;
    #pragma unroll
    for (int j = 0; j < 16; j++) {
      H[j] = fmaf(a_[j], H[j], (1.f - a_[j]) * k_[j] * g);
      yp = fmaf(q_[j], H[j], yp);
    }
    yb[(size_t)t * 256 + w * 64 + lane] = yp;
  }
}

// ---------------------------------------------------------------------------
// Wo transpose (2048x64 -> 64x2048) so K3's inner loop reads coalesced.
// ---------------------------------------------------------------------------
__global__ __launch_bounds__(256) void k_trans(const float* __restrict__ Wo,
                                               float* __restrict__ WoT) {
  int i = blockIdx.x * 256 + threadIdx.x;   // over 64*2048
  int d = i >> 11;
  int c = i & 2047;
  WoT[i] = Wo[(size_t)c * 64 + d];
}

// ---------------------------------------------------------------------------
// K3: sum y-partials, RMS-norm over 64, * norm_w, then yn @ Wo^T.
// Block = 16 rows x 512 cols; grid (512, 4) = 2048 blocks (8/CU).
// ---------------------------------------------------------------------------
__global__ __launch_bounds__(256) void k_out(const float* __restrict__ ypart,
    const float* __restrict__ norm_w, const float* __restrict__ WoT,
    float* __restrict__ out)
{
  __shared__ __align__(16) float yn[16 * 64];
  const int tid = threadIdx.x;
  const int r0  = blockIdx.x * 16;
  const int c0  = blockIdx.y * 512;
  {
    const int r = tid >> 4;          // 0..15
    const int d = (tid & 15) * 4;    // 0..60
    const float* yp = ypart + (size_t)(r0 + r) * 256;
    float4 y0 = *(const float4*)(yp + d);
    float4 y1 = *(const float4*)(yp + 64 + d);
    float4 y2 = *(const float4*)(yp + 128 + d);
    float4 y3 = *(const float4*)(yp + 192 + d);
    float yx = y0.x + y1.x + y2.x + y3.x;
    float yy = y0.y + y1.y + y2.y + y3.y;
    float yz = y0.z + y1.z + y2.z + y3.z;
    float yw = y0.w + y1.w + y2.w + y3.w;
    float sq = yx * yx + yy * yy + yz * yz + yw * yw;
    sq += __shfl_xor(sq, 1, 64);
    sq += __shfl_xor(sq, 2, 64);
    sq += __shfl_xor(sq, 4, 64);
    sq += __shfl_xor(sq, 8, 64);   // 16 threads per row, group-aligned
    float rms = rsqrtf(sq * (1.f / 64.f) + 1e-6f);
    float4 nw = *(const float4*)(norm_w + d);
    yn[r * 64 + d + 0] = yx * rms * nw.x;
    yn[r * 64 + d + 1] = yy * rms * nw.y;
    yn[r * 64 + d + 2] = yz * rms * nw.z;
    yn[r * 64 + d + 3] = yw * rms * nw.w;
  }
  __syncthreads();
  const int ctq = tid & 127;   // col quad
  const int rt  = tid >> 7;    // 0..1 -> 8 rows each
  float acc[8][4];
  #pragma unroll
  for (int r = 0; r < 8; r++) { acc[r][0] = 0.f; acc[r][1] = 0.f; acc[r][2] = 0.f; acc[r][3] = 0.f; }
  #pragma unroll 8
  for (int d = 0; d < 64; d++) {
    float4 wv = *(const float4*)(WoT + (size_t)d * 2048 + c0 + ctq * 4);
    #pragma unroll
    for (int r = 0; r < 8; r++) {
      float yv = yn[(rt * 8 + r) * 64 + d];
      acc[r][0] = fmaf(yv, wv.x, acc[r][0]);
      acc[r][1] = fmaf(yv, wv.y, acc[r][1]);
      acc[r][2] = fmaf(yv, wv.z, acc[r][2]);
      acc[r][3] = fmaf(yv, wv.w, acc[r][3]);
    }
  }
  #pragma unroll
  for (int r = 0; r < 8; r++) {
    float4 o; o.x = acc[r][0]; o.y = acc[r][1]; o.z = acc[r][2]; o.w = acc[r][3];
    *(float4*)(out + (size_t)(r0 + rt * 8 + r) * 2048 + c0 + ctq * 4) = o;
  }
}

extern "C" void kernel_launch(void* const* d_in, const int* in_sizes, int n_in,
                              void* d_out, int out_size, void* d_ws, size_t ws_size,
                              hipStream_t stream) {
  const float* x   = (const float*)d_in[0];
  const float* Wk  = (const float*)d_in[1];
  const float* Wv  = (const float*)d_in[2];
  const float* Wq  = (const float*)d_in[3];
  const float* Wa  = (const float*)d_in[4];
  const float* Wab = (const float*)d_in[5];
  const float* lam = (const float*)d_in[6];
  const float* nw  = (const float*)d_in[7];
  const float* Wo  = (const float*)d_in[8];
  float* out = (float*)d_out;

  float* wsf   = (float*)d_ws;
  float* proj  = wsf;                 // B*S*256 = 2,097,152 floats
  float* ypart = wsf + 2097152;       // B*S*4*64 = 2,097,152 floats
  float* WoT   = wsf + 4194304;       // 64*2048 = 131,072 floats

  k_trans<<<dim3(512), dim3(256), 0, stream>>>(Wo, WoT);
  k_proj <<<dim3(512), dim3(256), 0, stream>>>(x, Wk, Wv, Wq, Wa, Wab, lam, proj);
  k_scan <<<dim3(4),   dim3(256), 0, stream>>>(proj, ypart);
  k_out  <<<dim3(512, 4), dim3(256), 0, stream>>>(ypart, nw, WoT, out);
}